// Round 7
// baseline (1124.352 us; speedup 1.0000x reference)
//
#include <hip/hip_runtime.h>

#define BB 16
#define CC 256
#define NN 4096
#define MM 1024
#define EPSV 1e-5f
#define SCALE (1.0f/16.0f)   // 1/sqrt(C)

// ---- workspace layout (float offsets). Fixed part 23,499,776 floats = ~94 MB ----
#define OFF_MU    0            // 4096
#define OFF_SCORE 4096         // 65536   (dead after select)
#define OFF_IDX   69632        // 32768 ints (idx_s then idx_g)
#define OFF_U     102400       // 65536
#define OFF_WVZ   167936       // 65536
#define OFF_WF12  233472       // 65536
#define OFF_BVZ   299008       // 256
#define OFF_BZ    299264       // 256
#define OFF_W16   299520       // 4 bf16 weight mats = 131072 floats
#define OFF_XG    430592       // Xg bf16 [16*1024][256] = 2097152 floats
#define OFF_K16   2527744      // K bf16 [B][M][C] = 2097152 floats
#define OFF_VT16  4624896      // Vt bf16 [B][C][M] = 2097152 floats
#define OFF_Z     6722048      // 16777216 floats
#define OFF_BN    23499264     // 512
#define FIXED_F   23499776     // end of fixed region (floats)

typedef __attribute__((ext_vector_type(8))) short s16x8;
typedef __attribute__((ext_vector_type(4))) float f32x4;

__device__ __forceinline__ unsigned short f2bf(float f) {
    unsigned int u = __float_as_uint(f);
    return (unsigned short)((u + 0x7FFFu + ((u >> 16) & 1u)) >> 16);
}
__device__ __forceinline__ float bf2f(unsigned short h) {
    return __uint_as_float(((unsigned int)h) << 16);
}

__global__ __launch_bounds__(256) void zero_bn_kernel(float* bn) {
    int t = threadIdx.x;
    bn[t] = 0.f; bn[t + CC] = 0.f;
}

__global__ __launch_bounds__(256) void zero_rsum_kernel(float* r) {
    r[blockIdx.x * 256 + threadIdx.x] = 0.f;
}

// mu[b,c] = mean over n of x[b,c,n]  (float4 loads, 4 iters/thread)
__global__ __launch_bounds__(256) void mean_kernel(const float* __restrict__ x, float* __restrict__ mu) {
    int c = blockIdx.x, b = blockIdx.y, t = threadIdx.x;
    const float4* p = (const float4*)(x + ((size_t)b * CC + c) * NN);
    float s = 0.f;
    for (int n = t; n < NN / 4; n += 256) { float4 v = p[n]; s += (v.x + v.y) + (v.z + v.w); }
    __shared__ float red[256];
    red[t] = s; __syncthreads();
    for (int w = 128; w > 0; w >>= 1) { if (t < w) red[t] += red[t + w]; __syncthreads(); }
    if (t == 0) mu[b * CC + c] = red[0] * (1.0f / NN);
}

// x [B][C][N] f32 -> xT16 [B][N][C] bf16, fused with score accumulation
__global__ __launch_bounds__(256) void transpose_score_kernel(const float* __restrict__ x,
                                                              const float* __restrict__ mu,
                                                              unsigned short* __restrict__ xT,
                                                              float* __restrict__ score) {
    __shared__ float tile[32][33];
    __shared__ float smu[32];
    int b = blockIdx.z, c0 = blockIdx.y * 32, n0 = blockIdx.x * 32, t = threadIdx.x;
    int nl = t & 31, cr = t >> 5;
    if (t < 32) smu[t] = mu[b * CC + c0 + t];
#pragma unroll
    for (int q = 0; q < 4; ++q)
        tile[cr + q * 8][nl] = x[((size_t)b * CC + c0 + cr + q * 8) * NN + n0 + nl];
    __syncthreads();
    int nr = t >> 3, cq = t & 7;
    uint2 p;
    p.x = (unsigned int)f2bf(tile[cq * 4 + 0][nr]) | ((unsigned int)f2bf(tile[cq * 4 + 1][nr]) << 16);
    p.y = (unsigned int)f2bf(tile[cq * 4 + 2][nr]) | ((unsigned int)f2bf(tile[cq * 4 + 3][nr]) << 16);
    *(uint2*)&xT[((size_t)b * NN + n0 + nr) * CC + c0 + cq * 4] = p;
    int n = t & 31, cseg = t >> 5;
    float part = 0.f;
#pragma unroll
    for (int q = 0; q < 4; ++q) {
        float d = tile[cseg * 4 + q][n] - smu[cseg * 4 + q];
        part += d * d;
    }
    __syncthreads();
    tile[n][cseg] = part;
    __syncthreads();
    if (t < 32) {
        float s = 0.f;
#pragma unroll
        for (int j = 0; j < 8; ++j) s += tile[t][j];
        atomicAdd(&score[(size_t)b * NN + n0 + t], s);
    }
}

// radix-select: per batch, top-1024 set -> idx_s, bottom-1024 set -> idx_g (order arbitrary)
__global__ __launch_bounds__(1024) void select_kernel(const float* __restrict__ score,
                                                      int* __restrict__ idx_s, int* __restrict__ idx_g) {
    int b = blockIdx.x, t = threadIdx.x;
    __shared__ unsigned int keys[NN];
    __shared__ unsigned int hist[256];
    __shared__ unsigned int sbin, skrem;
    __shared__ int outcnt, eqcnt;
    __shared__ int eqidx[NN];
    for (int q = t; q < NN; q += 1024) keys[q] = __float_as_uint(score[(size_t)b * NN + q]);
    __syncthreads();
    for (int r = 0; r < 2; ++r) {
        unsigned int flip = r ? 0xFFFFFFFFu : 0u;
        unsigned int prefix = 0u, pmask = 0u;
        unsigned int k = MM;
        for (int pass = 0; pass < 4; ++pass) {
            int shift = 24 - 8 * pass;
            if (t < 256) hist[t] = 0u;
            __syncthreads();
            for (int q = t; q < NN; q += 1024) {
                unsigned int kv = keys[q] ^ flip;
                if ((kv & pmask) == prefix) atomicAdd(&hist[(kv >> shift) & 255u], 1u);
            }
            __syncthreads();
            for (int off = 1; off < 256; off <<= 1) {
                unsigned int v = 0u;
                if (t < 256) v = hist[t] + ((t + off < 256) ? hist[t + off] : 0u);
                __syncthreads();
                if (t < 256) hist[t] = v;
                __syncthreads();
            }
            if (t < 256) {
                unsigned int sj = hist[t], sj1 = (t < 255) ? hist[t + 1] : 0u;
                if (sj >= k && sj1 < k) { sbin = (unsigned int)t; skrem = k - sj1; }
            }
            __syncthreads();
            prefix |= sbin << shift;
            pmask |= 0xFFu << shift;
            k = skrem;
            __syncthreads();
        }
        unsigned int T = prefix;
        unsigned int krem = k;
        int* outp = r ? idx_g : idx_s;
        if (t == 0) { outcnt = 0; eqcnt = 0; }
        __syncthreads();
        for (int q = t; q < NN; q += 1024) {
            unsigned int kv = keys[q] ^ flip;
            if (kv > T) { int pp = atomicAdd(&outcnt, 1); outp[(size_t)b * MM + pp] = q; }
            else if (kv == T) { int pp = atomicAdd(&eqcnt, 1); eqidx[pp] = q; }
        }
        __syncthreads();
        int ne = eqcnt;
        for (int i = t; i < ne; i += 1024) {
            int me = eqidx[i];
            int rank = 0;
            for (int j = 0; j < ne; ++j) rank += (eqidx[j] < me) ? 1 : 0;
            if (rank < (int)krem) { int pp = atomicAdd(&outcnt, 1); outp[(size_t)b * MM + pp] = me; }
        }
        __syncthreads();
    }
}

__global__ __launch_bounds__(256) void smallmm_kernel(const float* __restrict__ A, int lda, int aoff,
                                                      const float* __restrict__ Bm, float* __restrict__ Cm) {
    int e = blockIdx.x, t = threadIdx.x;
    __shared__ float arow[CC];
    arow[t] = A[e * lda + aoff + t];
    __syncthreads();
    float acc = 0.f;
    for (int k = 0; k < CC; ++k) acc += arow[k] * Bm[k * CC + t];
    Cm[e * CC + t] = acc;
}

__global__ __launch_bounds__(256) void bvz_kernel(const float* __restrict__ U, const float* __restrict__ bv,
                                                  float* __restrict__ bvz) {
    int e = threadIdx.x;
    float acc = 0.f;
    for (int d = 0; d < CC; ++d) acc += U[e * CC + d] * bv[d];
    bvz[e] = acc;
}

__global__ __launch_bounds__(256) void bz_kernel(const float* __restrict__ Wf, const float* __restrict__ bf,
                                                 const float* __restrict__ bo_s, const float* __restrict__ bo_g,
                                                 float* __restrict__ bz) {
    int e = threadIdx.x;
    float acc = bf[e];
    for (int c = 0; c < CC; ++c)
        acc += Wf[e * 2 * CC + c] * bo_s[c] + Wf[e * 2 * CC + CC + c] * bo_g[c];
    bz[e] = acc;
}

__global__ __launch_bounds__(256) void wf12_kernel(const float* __restrict__ Wf, float* __restrict__ Wf12) {
    int e = blockIdx.x, c = threadIdx.x;
    Wf12[e * CC + c] = Wf[e * 2 * CC + c] + Wf[e * 2 * CC + CC + c];
}

__global__ __launch_bounds__(256) void conv_bf16_kernel(const float* __restrict__ src,
                                                        unsigned short* __restrict__ dst) {
    int i = blockIdx.x * 256 + threadIdx.x;
    float4 v = *(const float4*)(src + (size_t)i * 4);
    uint2 p;
    p.x = (unsigned int)f2bf(v.x) | ((unsigned int)f2bf(v.y) << 16);
    p.y = (unsigned int)f2bf(v.z) | ((unsigned int)f2bf(v.w) << 16);
    *(uint2*)&dst[(size_t)i * 4] = p;
}

__global__ __launch_bounds__(256) void gather_kernel(const unsigned short* __restrict__ xT,
                                                     const int* __restrict__ idx,
                                                     unsigned short* __restrict__ Xg) {
    int row = blockIdx.x * 4 + (threadIdx.x >> 6);
    int l = threadIdx.x & 63;
    int b = row >> 10, m = row & (MM - 1);
    int src = idx[b * MM + m];
    *(uint2*)&Xg[(size_t)row * CC + l * 4] =
        *(const uint2*)&xT[((size_t)b * NN + src) * CC + l * 4];
}

// ---- generic bf16 MFMA GEMM: out[i][j] = sum_k A[i][k]*Bw[j][k] (+bias), 128x128 tile ----
template<int OMODE>
__global__ __launch_bounds__(256, 3) void gemm_bt(
    const unsigned short* __restrict__ A, size_t a_bs,
    const unsigned short* __restrict__ Bw, size_t b_bs,
    const float* __restrict__ bias,
    void* __restrict__ outp, size_t o_bs, int ldo)
{
    __shared__ __align__(16) unsigned short As[128 * 32];
    __shared__ __align__(16) unsigned short Bs[128 * 32];
    int z = blockIdx.z;
    const unsigned short* Ab = A + z * a_bs + (size_t)blockIdx.x * 128 * CC;
    const unsigned short* Bb = Bw + z * b_bs + (size_t)blockIdx.y * 128 * CC;
    int t = threadIdx.x, w = t >> 6, l = t & 63, g = l >> 4, c16 = l & 15;
    int wi = w >> 1, wj = w & 1;
    int srow = t >> 2, skq = (t & 3) * 8;

    f32x4 acc[4][4];
#pragma unroll
    for (int a = 0; a < 4; ++a)
#pragma unroll
        for (int bq = 0; bq < 4; ++bq) acc[a][bq] = (f32x4){0.f, 0.f, 0.f, 0.f};

    for (int ks = 0; ks < 8; ++ks) {
        int k0 = ks * 32;
        uint4 a0 = *(const uint4*)(Ab + (size_t)srow * CC + k0 + skq);
        uint4 a1 = *(const uint4*)(Ab + (size_t)(srow + 64) * CC + k0 + skq);
        uint4 b0 = *(const uint4*)(Bb + (size_t)srow * CC + k0 + skq);
        uint4 b1 = *(const uint4*)(Bb + (size_t)(srow + 64) * CC + k0 + skq);
        __syncthreads();
        *(uint4*)&As[srow * 32 + skq] = a0;
        *(uint4*)&As[(srow + 64) * 32 + skq] = a1;
        *(uint4*)&Bs[srow * 32 + skq] = b0;
        *(uint4*)&Bs[(srow + 64) * 32 + skq] = b1;
        __syncthreads();
        s16x8 af[4], bf4[4];
#pragma unroll
        for (int fi = 0; fi < 4; ++fi)
            af[fi] = *(const s16x8*)&As[(wi * 64 + fi * 16 + c16) * 32 + g * 8];
#pragma unroll
        for (int fj = 0; fj < 4; ++fj)
            bf4[fj] = *(const s16x8*)&Bs[(wj * 64 + fj * 16 + c16) * 32 + g * 8];
#pragma unroll
        for (int fi = 0; fi < 4; ++fi)
#pragma unroll
            for (int fj = 0; fj < 4; ++fj)
                acc[fi][fj] = __builtin_amdgcn_mfma_f32_16x16x32_bf16(af[fi], bf4[fj], acc[fi][fj], 0, 0, 0);
    }

    int i0 = blockIdx.x * 128 + wi * 64, j0 = blockIdx.y * 128 + wj * 64;
#pragma unroll
    for (int fi = 0; fi < 4; ++fi) {
#pragma unroll
        for (int fj = 0; fj < 4; ++fj) {
            int colg = j0 + fj * 16 + c16;
#pragma unroll
            for (int r = 0; r < 4; ++r) {
                int rowg = i0 + fi * 16 + g * 4 + r;
                float v = acc[fi][fj][r] + (OMODE == 2 ? bias[rowg] : bias[colg]);
                if (OMODE == 0)
                    ((float*)outp)[z * o_bs + (size_t)rowg * ldo + colg] = v;
                else
                    ((unsigned short*)outp)[z * o_bs + (size_t)rowg * ldo + colg] = f2bf(v);
            }
        }
    }
}

// ---- fused flash-style attention: Z[z][n][e] += (exp(Q·K^T/16)·V) / rsum[n] ----
// One block = 64 Q-rows; 4 waves as 2n x 2{m/e}, R=2 row-frags/wave (round 6's LDS-
// ratio fix kept). 256-thread blocks with ~40.5KB LDS -> 2 independent blocks/CU:
// round 6's 512-thread version padded LDS to 113KB = 1 block/CU, so all 8 waves
// stalled at the same 4 block-wide barriers/tile (dur 186us vs ~92us of accounted
// work). Two co-resident blocks give cross-block overlap at barriers (m114).
// amdgpu_waves_per_eu(2,2) keeps the 256-VGPR budget (no spill, rounds 5-6 verified).
__global__ __attribute__((amdgpu_flat_work_group_size(256, 256)))
__attribute__((amdgpu_waves_per_eu(2, 2)))
void fused_attn(
    const unsigned short* __restrict__ Q,    // [B][N][C] bf16 (bias included)
    const unsigned short* __restrict__ K,    // [B][M][C] bf16 (bias included)
    const unsigned short* __restrict__ Vt,   // [B][C][M] bf16 (bias included)
    float* __restrict__ Z)                   // [B][N][C] +=
{
    __shared__ __align__(16) unsigned char KV[64 * 512];   // K view [64][256]bf16 / V view [256][64]bf16
    __shared__ __align__(16) unsigned char Ps[64 * 128];   // P [64][64] bf16
    __shared__ float rsl[2][64];

    int z = blockIdx.z;
    int n0 = blockIdx.x * 64;
    int t = threadIdx.x, w = t >> 6, l = t & 63, g = l >> 4, c16 = l & 15;
    int wn = w >> 1, wc = w & 1;   // wave grid: 2 n-rows x 2 {m,e}-cols

    const unsigned short* Qb = Q + ((size_t)z * NN + n0) * CC;
    const unsigned short* Kz = K + (size_t)z * MM * CC;
    const unsigned short* Vz = Vt + (size_t)z * CC * MM;

    // Q fragments in registers: rows wn*32 + fi*16 + c16, k = ks*32 + g*8  (64 VGPR)
    s16x8 q[2][8];
#pragma unroll
    for (int fi = 0; fi < 2; ++fi)
#pragma unroll
        for (int ks = 0; ks < 8; ++ks)
            q[fi][ks] = *(const s16x8*)&Qb[(size_t)(wn * 32 + fi * 16 + c16) * CC + ks * 32 + g * 8];

    f32x4 o[2][8];
#pragma unroll
    for (int fi = 0; fi < 2; ++fi)
#pragma unroll
        for (int fj = 0; fj < 8; ++fj) o[fi][fj] = (f32x4){0.f, 0.f, 0.f, 0.f};
    float rs[2][4];
#pragma unroll
    for (int fi = 0; fi < 2; ++fi)
#pragma unroll
        for (int r = 0; r < 4; ++r) rs[fi][r] = 0.f;

    // prefetch K tile 0 into registers (256 threads: 8 x uint4 per thread = 32KB)
    uint4 kr[8];
#pragma unroll
    for (int i = 0; i < 8; ++i) {
        int c = i * 256 + t, row = c >> 5, kc = c & 31;
        kr[i] = *(const uint4*)&Kz[(size_t)row * CC + kc * 8];
    }

    for (int mt = 0; mt < 16; ++mt) {
        int m0 = mt * 64;
        __syncthreads();                       // prev PV reads of KV done
        // store K tile (swizzled)
#pragma unroll
        for (int i = 0; i < 8; ++i) {
            int c = i * 256 + t, row = c >> 5, kc = c & 31;
            *(uint4*)(KV + row * 512 + ((kc * 16) ^ ((row & 7) << 4))) = kr[i];
        }
        __syncthreads();                       // K visible
        // prefetch V tile (overlaps QK)
        uint4 vr[8];
#pragma unroll
        for (int i = 0; i < 8; ++i) {
            int c = i * 256 + t, row = c >> 3, mc = c & 7;
            vr[i] = *(const uint4*)&Vz[(size_t)row * MM + m0 + mc * 8];
        }
        // QK^T: rows [wn*32,+32) x m-cols [wc*32,+32)
        f32x4 sacc[2][2];
#pragma unroll
        for (int fi = 0; fi < 2; ++fi)
#pragma unroll
            for (int fj = 0; fj < 2; ++fj) sacc[fi][fj] = (f32x4){0.f, 0.f, 0.f, 0.f};
        __builtin_amdgcn_s_setprio(1);
#pragma unroll
        for (int ks = 0; ks < 8; ++ks) {
            s16x8 kf[2];
#pragma unroll
            for (int fj = 0; fj < 2; ++fj) {
                int mr = wc * 32 + fj * 16 + c16;
                kf[fj] = *(const s16x8*)(KV + ((mr * 512 + ks * 64 + g * 16) ^ ((mr & 7) << 4)));
            }
#pragma unroll
            for (int fi = 0; fi < 2; ++fi)
#pragma unroll
                for (int fj = 0; fj < 2; ++fj)
                    sacc[fi][fj] = __builtin_amdgcn_mfma_f32_16x16x32_bf16(q[fi][ks], kf[fj], sacc[fi][fj], 0, 0, 0);
        }
        __builtin_amdgcn_s_setprio(0);
        // exp -> P (LDS, swizzled), rsum partials
#pragma unroll
        for (int fi = 0; fi < 2; ++fi)
#pragma unroll
            for (int fj = 0; fj < 2; ++fj)
#pragma unroll
                for (int r = 0; r < 4; ++r) {
                    float e = __expf(sacc[fi][fj][r] * SCALE);
                    unsigned short h = f2bf(e);
                    int nr = wn * 32 + fi * 16 + g * 4 + r;
                    int mc = wc * 32 + fj * 16 + c16;
                    *(unsigned short*)(Ps + ((nr * 128 + mc * 2) ^ ((nr & 7) << 4))) = h;
                    rs[fi][r] += bf2f(h);
                }
        __syncthreads();                       // K reads done, P written
        // store V tile (overwrites K region, swizzled)
#pragma unroll
        for (int i = 0; i < 8; ++i) {
            int c = i * 256 + t, row = c >> 3, mc = c & 7;
            *(uint4*)(KV + row * 128 + ((mc * 16) ^ ((row & 7) << 4))) = vr[i];
        }
        // prefetch next K tile (overlaps PV)
        if (mt < 15) {
#pragma unroll
            for (int i = 0; i < 8; ++i) {
                int c = i * 256 + t, row = c >> 5, kc = c & 31;
                kr[i] = *(const uint4*)&Kz[(size_t)(m0 + 64 + row) * CC + kc * 8];
            }
        }
        __syncthreads();                       // V + P visible
        // PV: O += P · V ; rows [wn*32,+32) x e-cols [wc*128,+128)
        __builtin_amdgcn_s_setprio(1);
#pragma unroll
        for (int ks2 = 0; ks2 < 2; ++ks2) {
            s16x8 pa[2];
#pragma unroll
            for (int fi = 0; fi < 2; ++fi) {
                int nr = wn * 32 + fi * 16 + c16;
                pa[fi] = *(const s16x8*)(Ps + ((nr * 128 + ks2 * 64 + g * 16) ^ ((nr & 7) << 4)));
            }
#pragma unroll
            for (int fj = 0; fj < 8; ++fj) {
                int er = wc * 128 + fj * 16 + c16;
                s16x8 vb = *(const s16x8*)(KV + ((er * 128 + ks2 * 64 + g * 16) ^ ((er & 7) << 4)));
#pragma unroll
                for (int fi = 0; fi < 2; ++fi)
                    o[fi][fj] = __builtin_amdgcn_mfma_f32_16x16x32_bf16(pa[fi], vb, o[fi][fj], 0, 0, 0);
            }
        }
        __builtin_amdgcn_s_setprio(0);
    }

    // cross-lane + cross-wave rsum
#pragma unroll
    for (int fi = 0; fi < 2; ++fi)
#pragma unroll
        for (int r = 0; r < 4; ++r) {
            float v = rs[fi][r];
            v += __shfl_xor(v, 1); v += __shfl_xor(v, 2);
            v += __shfl_xor(v, 4); v += __shfl_xor(v, 8);
            if (c16 == 0) rsl[wc][wn * 32 + fi * 16 + g * 4 + r] = v;
        }
    __syncthreads();
    float* Zb = Z + ((size_t)z * NN + n0) * CC;
#pragma unroll
    for (int fi = 0; fi < 2; ++fi)
#pragma unroll
        for (int r = 0; r < 4; ++r) {
            int nr = wn * 32 + fi * 16 + g * 4 + r;
            float inv = 1.0f / (rsl[0][nr] + rsl[1][nr]);
#pragma unroll
            for (int fj = 0; fj < 8; ++fj) {
                int e = wc * 128 + fj * 16 + c16;
                Zb[(size_t)nr * CC + e] += o[fi][fj][r] * inv;
            }
        }
}

// BN stats: per-channel sum and sumsq over B*N rows of Z [B*N][C]
__global__ __launch_bounds__(256) void bn_stats_kernel(const float* __restrict__ Z, float* __restrict__ bn) {
    int blk = blockIdx.x, e = threadIdx.x;
    const float* p = Z + (size_t)blk * 256 * CC + e;
    float s1 = 0.f, s2 = 0.f;
    for (int r = 0; r < 256; ++r) { float v = p[(size_t)r * CC]; s1 += v; s2 += v * v; }
    atomicAdd(&bn[e], s1);
    atomicAdd(&bn[CC + e], s2);
}

// normalize + relu + transpose [B][N][C] -> [B][C][N]
__global__ __launch_bounds__(256) void bn_apply_kernel(const float* __restrict__ Z, const float* __restrict__ bn,
                                                       const float* __restrict__ gamma, const float* __restrict__ beta,
                                                       float* __restrict__ out) {
    int b = blockIdx.z, e0 = blockIdx.y * 32, n0 = blockIdx.x * 32, t = threadIdx.x;
    __shared__ float tile[32][33];
    int c = t & 31, r0 = (t >> 5) * 4;
#pragma unroll
    for (int q = 0; q < 4; ++q)
        tile[r0 + q][c] = Z[((size_t)b * NN + n0 + r0 + q) * CC + e0 + c];
    __syncthreads();
    int n = t & 31, er0 = (t >> 5) * 4;
    const float invcnt = 1.0f / (BB * NN);
#pragma unroll
    for (int q = 0; q < 4; ++q) {
        int e = e0 + er0 + q;
        float mean = bn[e] * invcnt;
        float var = bn[CC + e] * invcnt - mean * mean;
        float rsq = rsqrtf(var + EPSV);
        float v = (tile[n][er0 + q] - mean) * rsq * gamma[e] + beta[e];
        out[((size_t)b * CC + e) * NN + n0 + n] = fmaxf(v, 0.f);
    }
}

extern "C" void kernel_launch(void* const* d_in, const int* in_sizes, int n_in,
                              void* d_out, int out_size, void* d_ws, size_t ws_size,
                              hipStream_t stream) {
    const float* x    = (const float*)d_in[0];
    const float* Wq_s = (const float*)d_in[2];  const float* bq_s = (const float*)d_in[3];
    const float* Wk_s = (const float*)d_in[4];  const float* bk_s = (const float*)d_in[5];
    const float* Wv_s = (const float*)d_in[6];  const float* bv_s = (const float*)d_in[7];
    const float* Wo_s = (const float*)d_in[8];  const float* bo_s = (const float*)d_in[9];
    const float* Wq_g = (const float*)d_in[10]; const float* bq_g = (const float*)d_in[11];
    const float* Wk_g = (const float*)d_in[12]; const float* bk_g = (const float*)d_in[13];
    const float* Wv_g = (const float*)d_in[14]; const float* bv_g = (const float*)d_in[15];
    const float* Wo_g = (const float*)d_in[16]; const float* bo_g = (const float*)d_in[17];
    const float* Wf   = (const float*)d_in[18]; const float* bf   = (const float*)d_in[19];
    const float* gamma = (const float*)d_in[20]; const float* beta = (const float*)d_in[21];

    float* ws    = (float*)d_ws;
    float* mu    = ws + OFF_MU;
    float* score = ws + OFF_SCORE;
    int*   idx_s = (int*)(ws + OFF_IDX);
    int*   idx_g = idx_s + BB * MM;
    float* U     = ws + OFF_U;
    float* Wvz   = ws + OFF_WVZ;
    float* Wf12  = ws + OFF_WF12;
    float* bvz   = ws + OFF_BVZ;
    float* bz    = ws + OFF_BZ;
    unsigned short* Wf12_16 = (unsigned short*)(ws + OFF_W16);
    unsigned short* Wq16    = Wf12_16 + 65536;
    unsigned short* Wk16    = Wq16 + 65536;
    unsigned short* Wvz16   = Wk16 + 65536;
    unsigned short* Xg16 = (unsigned short*)(ws + OFF_XG);
    unsigned short* K16  = (unsigned short*)(ws + OFF_K16);
    unsigned short* Vt16 = (unsigned short*)(ws + OFF_VT16);
    float* Z     = ws + OFF_Z;
    float* bn    = ws + OFF_BN;
    // d_out doubles as scratch: first half Q16, second half xT16 (both dead before bn_apply)
    unsigned short* Q16  = (unsigned short*)d_out;
    unsigned short* xT16 = Q16 + (size_t)BB * NN * CC;

    zero_bn_kernel<<<1, 256, 0, stream>>>(bn);
    mean_kernel<<<dim3(CC, BB), 256, 0, stream>>>(x, mu);
    zero_rsum_kernel<<<BB * NN / 256, 256, 0, stream>>>(score);
    transpose_score_kernel<<<dim3(NN / 32, CC / 32, BB), 256, 0, stream>>>(x, mu, xT16, score);
    select_kernel<<<BB, 1024, 0, stream>>>(score, idx_s, idx_g);
    wf12_kernel<<<CC, 256, 0, stream>>>(Wf, Wf12);
    bz_kernel<<<1, 256, 0, stream>>>(Wf, bf, bo_s, bo_g, bz);
    conv_bf16_kernel<<<64, 256, 0, stream>>>(Wf12, Wf12_16);
    // Z = xT @ Wf12^T + bz  (residual x through both conv halves)
    gemm_bt<0><<<dim3(512, 2, 1), 256, 0, stream>>>(xT16, 0, Wf12_16, 0, bz, Z, 0, CC);

    for (int br = 0; br < 2; ++br) {
        const float* Wo = br ? Wo_g : Wo_s;
        const float* Wv = br ? Wv_g : Wv_s;  const float* bv = br ? bv_g : bv_s;
        const float* Wk = br ? Wk_g : Wk_s;  const float* bk = br ? bk_g : bk_s;
        const float* Wq = br ? Wq_g : Wq_s;  const float* bq = br ? bq_g : bq_s;
        int* idx = br ? idx_g : idx_s;
        int aoff = br ? CC : 0;
        // U = Wf_half @ Wo ; Wvz = U @ Wv ; bvz = U @ bv
        smallmm_kernel<<<CC, 256, 0, stream>>>(Wf, 2 * CC, aoff, Wo, U);
        smallmm_kernel<<<CC, 256, 0, stream>>>(U, CC, 0, Wv, Wvz);
        bvz_kernel<<<1, 256, 0, stream>>>(U, bv, bvz);
        conv_bf16_kernel<<<64, 256, 0, stream>>>(Wq, Wq16);
        conv_bf16_kernel<<<64, 256, 0, stream>>>(Wk, Wk16);
        conv_bf16_kernel<<<64, 256, 0, stream>>>(Wvz, Wvz16);
        // gather context rows once, then all projections are plain A*B^T GEMMs
        gather_kernel<<<BB * MM / 4, 256, 0, stream>>>(xT16, idx, Xg16);
        gemm_bt<1><<<dim3(BB * MM / 128, 2, 1), 256, 0, stream>>>(Xg16, 0, Wk16, 0, bk, K16, 0, CC);
        gemm_bt<2><<<dim3(2, 8, BB), 256, 0, stream>>>(Wvz16, 0, Xg16, (size_t)MM * CC, bvz,
                                                       Vt16, (size_t)CC * MM, MM);
        gemm_bt<1><<<dim3(512, 2, 1), 256, 0, stream>>>(xT16, 0, Wq16, 0, bq, Q16, 0, CC);

        // fused flash attention: Z += softmax(Q·K^T/16)·V  (P never touches HBM)
        fused_attn<<<dim3(NN / 64, 1, BB), 256, 0, stream>>>(Q16, K16, Vt16, Z);
    }

    bn_stats_kernel<<<BB * NN / 256, 256, 0, stream>>>(Z, bn);
    bn_apply_kernel<<<dim3(NN / 32, CC / 32, BB), 256, 0, stream>>>(Z, bn, gamma, beta, (float*)d_out);
}

// Round 8
// 898.511 us; speedup vs baseline: 1.2514x; 1.2514x over previous
//
#include <hip/hip_runtime.h>

#define BB 16
#define CC 256
#define NN 4096
#define MM 1024
#define EPSV 1e-5f
#define SCALE (1.0f/16.0f)   // 1/sqrt(C)

// ---- workspace layout (float offsets). Fixed part 23,499,776 floats = ~94 MB ----
#define OFF_MU    0            // 4096
#define OFF_SCORE 4096         // 65536   (dead after select)
#define OFF_IDX   69632        // 32768 ints (idx_s then idx_g)
#define OFF_U     102400       // 65536
#define OFF_WVZ   167936       // 65536
#define OFF_WF12  233472       // 65536
#define OFF_BVZ   299008       // 256
#define OFF_BZ    299264       // 256
#define OFF_W16   299520       // 4 bf16 weight mats = 131072 floats
#define OFF_XG    430592       // Xg bf16 [16*1024][256] = 2097152 floats
#define OFF_K16   2527744      // K bf16 [B][M][C] = 2097152 floats
#define OFF_VT16  4624896      // Vt bf16 [B][C][M] = 2097152 floats
#define OFF_Z     6722048      // 16777216 floats
#define OFF_BN    23499264     // 512
#define FIXED_F   23499776     // end of fixed region (floats)

typedef __attribute__((ext_vector_type(8))) short s16x8;
typedef __attribute__((ext_vector_type(4))) float f32x4;

__device__ __forceinline__ unsigned short f2bf(float f) {
    unsigned int u = __float_as_uint(f);
    return (unsigned short)((u + 0x7FFFu + ((u >> 16) & 1u)) >> 16);
}
__device__ __forceinline__ float bf2f(unsigned short h) {
    return __uint_as_float(((unsigned int)h) << 16);
}

__global__ __launch_bounds__(256) void zero_bn_kernel(float* bn) {
    int t = threadIdx.x;
    bn[t] = 0.f; bn[t + CC] = 0.f;
}

__global__ __launch_bounds__(256) void zero_rsum_kernel(float* r) {
    r[blockIdx.x * 256 + threadIdx.x] = 0.f;
}

// mu[b,c] = mean over n of x[b,c,n]  (float4 loads, 4 iters/thread)
__global__ __launch_bounds__(256) void mean_kernel(const float* __restrict__ x, float* __restrict__ mu) {
    int c = blockIdx.x, b = blockIdx.y, t = threadIdx.x;
    const float4* p = (const float4*)(x + ((size_t)b * CC + c) * NN);
    float s = 0.f;
    for (int n = t; n < NN / 4; n += 256) { float4 v = p[n]; s += (v.x + v.y) + (v.z + v.w); }
    __shared__ float red[256];
    red[t] = s; __syncthreads();
    for (int w = 128; w > 0; w >>= 1) { if (t < w) red[t] += red[t + w]; __syncthreads(); }
    if (t == 0) mu[b * CC + c] = red[0] * (1.0f / NN);
}

// x [B][C][N] f32 -> xT16 [B][N][C] bf16, fused with score accumulation
__global__ __launch_bounds__(256) void transpose_score_kernel(const float* __restrict__ x,
                                                              const float* __restrict__ mu,
                                                              unsigned short* __restrict__ xT,
                                                              float* __restrict__ score) {
    __shared__ float tile[32][33];
    __shared__ float smu[32];
    int b = blockIdx.z, c0 = blockIdx.y * 32, n0 = blockIdx.x * 32, t = threadIdx.x;
    int nl = t & 31, cr = t >> 5;
    if (t < 32) smu[t] = mu[b * CC + c0 + t];
#pragma unroll
    for (int q = 0; q < 4; ++q)
        tile[cr + q * 8][nl] = x[((size_t)b * CC + c0 + cr + q * 8) * NN + n0 + nl];
    __syncthreads();
    int nr = t >> 3, cq = t & 7;
    uint2 p;
    p.x = (unsigned int)f2bf(tile[cq * 4 + 0][nr]) | ((unsigned int)f2bf(tile[cq * 4 + 1][nr]) << 16);
    p.y = (unsigned int)f2bf(tile[cq * 4 + 2][nr]) | ((unsigned int)f2bf(tile[cq * 4 + 3][nr]) << 16);
    *(uint2*)&xT[((size_t)b * NN + n0 + nr) * CC + c0 + cq * 4] = p;
    int n = t & 31, cseg = t >> 5;
    float part = 0.f;
#pragma unroll
    for (int q = 0; q < 4; ++q) {
        float d = tile[cseg * 4 + q][n] - smu[cseg * 4 + q];
        part += d * d;
    }
    __syncthreads();
    tile[n][cseg] = part;
    __syncthreads();
    if (t < 32) {
        float s = 0.f;
#pragma unroll
        for (int j = 0; j < 8; ++j) s += tile[t][j];
        atomicAdd(&score[(size_t)b * NN + n0 + t], s);
    }
}

// radix-select: per batch, top-1024 set -> idx_s, bottom-1024 set -> idx_g (order arbitrary)
__global__ __launch_bounds__(1024) void select_kernel(const float* __restrict__ score,
                                                      int* __restrict__ idx_s, int* __restrict__ idx_g) {
    int b = blockIdx.x, t = threadIdx.x;
    __shared__ unsigned int keys[NN];
    __shared__ unsigned int hist[256];
    __shared__ unsigned int sbin, skrem;
    __shared__ int outcnt, eqcnt;
    __shared__ int eqidx[NN];
    for (int q = t; q < NN; q += 1024) keys[q] = __float_as_uint(score[(size_t)b * NN + q]);
    __syncthreads();
    for (int r = 0; r < 2; ++r) {
        unsigned int flip = r ? 0xFFFFFFFFu : 0u;
        unsigned int prefix = 0u, pmask = 0u;
        unsigned int k = MM;
        for (int pass = 0; pass < 4; ++pass) {
            int shift = 24 - 8 * pass;
            if (t < 256) hist[t] = 0u;
            __syncthreads();
            for (int q = t; q < NN; q += 1024) {
                unsigned int kv = keys[q] ^ flip;
                if ((kv & pmask) == prefix) atomicAdd(&hist[(kv >> shift) & 255u], 1u);
            }
            __syncthreads();
            for (int off = 1; off < 256; off <<= 1) {
                unsigned int v = 0u;
                if (t < 256) v = hist[t] + ((t + off < 256) ? hist[t + off] : 0u);
                __syncthreads();
                if (t < 256) hist[t] = v;
                __syncthreads();
            }
            if (t < 256) {
                unsigned int sj = hist[t], sj1 = (t < 255) ? hist[t + 1] : 0u;
                if (sj >= k && sj1 < k) { sbin = (unsigned int)t; skrem = k - sj1; }
            }
            __syncthreads();
            prefix |= sbin << shift;
            pmask |= 0xFFu << shift;
            k = skrem;
            __syncthreads();
        }
        unsigned int T = prefix;
        unsigned int krem = k;
        int* outp = r ? idx_g : idx_s;
        if (t == 0) { outcnt = 0; eqcnt = 0; }
        __syncthreads();
        for (int q = t; q < NN; q += 1024) {
            unsigned int kv = keys[q] ^ flip;
            if (kv > T) { int pp = atomicAdd(&outcnt, 1); outp[(size_t)b * MM + pp] = q; }
            else if (kv == T) { int pp = atomicAdd(&eqcnt, 1); eqidx[pp] = q; }
        }
        __syncthreads();
        int ne = eqcnt;
        for (int i = t; i < ne; i += 1024) {
            int me = eqidx[i];
            int rank = 0;
            for (int j = 0; j < ne; ++j) rank += (eqidx[j] < me) ? 1 : 0;
            if (rank < (int)krem) { int pp = atomicAdd(&outcnt, 1); outp[(size_t)b * MM + pp] = me; }
        }
        __syncthreads();
    }
}

__global__ __launch_bounds__(256) void smallmm_kernel(const float* __restrict__ A, int lda, int aoff,
                                                      const float* __restrict__ Bm, float* __restrict__ Cm) {
    int e = blockIdx.x, t = threadIdx.x;
    __shared__ float arow[CC];
    arow[t] = A[e * lda + aoff + t];
    __syncthreads();
    float acc = 0.f;
    for (int k = 0; k < CC; ++k) acc += arow[k] * Bm[k * CC + t];
    Cm[e * CC + t] = acc;
}

__global__ __launch_bounds__(256) void bvz_kernel(const float* __restrict__ U, const float* __restrict__ bv,
                                                  float* __restrict__ bvz) {
    int e = threadIdx.x;
    float acc = 0.f;
    for (int d = 0; d < CC; ++d) acc += U[e * CC + d] * bv[d];
    bvz[e] = acc;
}

__global__ __launch_bounds__(256) void bz_kernel(const float* __restrict__ Wf, const float* __restrict__ bf,
                                                 const float* __restrict__ bo_s, const float* __restrict__ bo_g,
                                                 float* __restrict__ bz) {
    int e = threadIdx.x;
    float acc = bf[e];
    for (int c = 0; c < CC; ++c)
        acc += Wf[e * 2 * CC + c] * bo_s[c] + Wf[e * 2 * CC + CC + c] * bo_g[c];
    bz[e] = acc;
}

__global__ __launch_bounds__(256) void wf12_kernel(const float* __restrict__ Wf, float* __restrict__ Wf12) {
    int e = blockIdx.x, c = threadIdx.x;
    Wf12[e * CC + c] = Wf[e * 2 * CC + c] + Wf[e * 2 * CC + CC + c];
}

__global__ __launch_bounds__(256) void conv_bf16_kernel(const float* __restrict__ src,
                                                        unsigned short* __restrict__ dst) {
    int i = blockIdx.x * 256 + threadIdx.x;
    float4 v = *(const float4*)(src + (size_t)i * 4);
    uint2 p;
    p.x = (unsigned int)f2bf(v.x) | ((unsigned int)f2bf(v.y) << 16);
    p.y = (unsigned int)f2bf(v.z) | ((unsigned int)f2bf(v.w) << 16);
    *(uint2*)&dst[(size_t)i * 4] = p;
}

__global__ __launch_bounds__(256) void gather_kernel(const unsigned short* __restrict__ xT,
                                                     const int* __restrict__ idx,
                                                     unsigned short* __restrict__ Xg) {
    int row = blockIdx.x * 4 + (threadIdx.x >> 6);
    int l = threadIdx.x & 63;
    int b = row >> 10, m = row & (MM - 1);
    int src = idx[b * MM + m];
    *(uint2*)&Xg[(size_t)row * CC + l * 4] =
        *(const uint2*)&xT[((size_t)b * NN + src) * CC + l * 4];
}

// ---- generic bf16 MFMA GEMM: out[i][j] = sum_k A[i][k]*Bw[j][k] (+bias), 128x128 tile ----
template<int OMODE>
__global__ __launch_bounds__(256, 3) void gemm_bt(
    const unsigned short* __restrict__ A, size_t a_bs,
    const unsigned short* __restrict__ Bw, size_t b_bs,
    const float* __restrict__ bias,
    void* __restrict__ outp, size_t o_bs, int ldo)
{
    __shared__ __align__(16) unsigned short As[128 * 32];
    __shared__ __align__(16) unsigned short Bs[128 * 32];
    int z = blockIdx.z;
    const unsigned short* Ab = A + z * a_bs + (size_t)blockIdx.x * 128 * CC;
    const unsigned short* Bb = Bw + z * b_bs + (size_t)blockIdx.y * 128 * CC;
    int t = threadIdx.x, w = t >> 6, l = t & 63, g = l >> 4, c16 = l & 15;
    int wi = w >> 1, wj = w & 1;
    int srow = t >> 2, skq = (t & 3) * 8;

    f32x4 acc[4][4];
#pragma unroll
    for (int a = 0; a < 4; ++a)
#pragma unroll
        for (int bq = 0; bq < 4; ++bq) acc[a][bq] = (f32x4){0.f, 0.f, 0.f, 0.f};

    for (int ks = 0; ks < 8; ++ks) {
        int k0 = ks * 32;
        uint4 a0 = *(const uint4*)(Ab + (size_t)srow * CC + k0 + skq);
        uint4 a1 = *(const uint4*)(Ab + (size_t)(srow + 64) * CC + k0 + skq);
        uint4 b0 = *(const uint4*)(Bb + (size_t)srow * CC + k0 + skq);
        uint4 b1 = *(const uint4*)(Bb + (size_t)(srow + 64) * CC + k0 + skq);
        __syncthreads();
        *(uint4*)&As[srow * 32 + skq] = a0;
        *(uint4*)&As[(srow + 64) * 32 + skq] = a1;
        *(uint4*)&Bs[srow * 32 + skq] = b0;
        *(uint4*)&Bs[(srow + 64) * 32 + skq] = b1;
        __syncthreads();
        s16x8 af[4], bf4[4];
#pragma unroll
        for (int fi = 0; fi < 4; ++fi)
            af[fi] = *(const s16x8*)&As[(wi * 64 + fi * 16 + c16) * 32 + g * 8];
#pragma unroll
        for (int fj = 0; fj < 4; ++fj)
            bf4[fj] = *(const s16x8*)&Bs[(wj * 64 + fj * 16 + c16) * 32 + g * 8];
#pragma unroll
        for (int fi = 0; fi < 4; ++fi)
#pragma unroll
            for (int fj = 0; fj < 4; ++fj)
                acc[fi][fj] = __builtin_amdgcn_mfma_f32_16x16x32_bf16(af[fi], bf4[fj], acc[fi][fj], 0, 0, 0);
    }

    int i0 = blockIdx.x * 128 + wi * 64, j0 = blockIdx.y * 128 + wj * 64;
#pragma unroll
    for (int fi = 0; fi < 4; ++fi) {
#pragma unroll
        for (int fj = 0; fj < 4; ++fj) {
            int colg = j0 + fj * 16 + c16;
#pragma unroll
            for (int r = 0; r < 4; ++r) {
                int rowg = i0 + fi * 16 + g * 4 + r;
                float v = acc[fi][fj][r] + (OMODE == 2 ? bias[rowg] : bias[colg]);
                if (OMODE == 0)
                    ((float*)outp)[z * o_bs + (size_t)rowg * ldo + colg] = v;
                else
                    ((unsigned short*)outp)[z * o_bs + (size_t)rowg * ldo + colg] = f2bf(v);
            }
        }
    }
}

// ---- fused flash-style attention: Z[z][n][e] += (exp(Q·K^T/16)·V) / rsum[n] ----
// Round-6 base (128 rows, 512 thr, R=2, waves_per_eu(2,2) = no spill) with the
// vmcnt-drain fix: separate K/V/P LDS buffers (dynamic 80KB) -> K and V stored in
// one window (3 barriers/tile, was 4); next-tile K+V prefetch issued right after
// the stores-visible barrier so it overlaps QK+exp+PV; the one barrier it must
// cross (P-visibility) is a RAW s_barrier + lgkmcnt(0) only -- no vmcnt(0) drain
// (the compiler's implicit drain at __syncthreads was serializing each tile's
// K-load latency into the critical path, ~8K stall cyc/tile in round 6).
__global__ __attribute__((amdgpu_flat_work_group_size(512, 512)))
__attribute__((amdgpu_waves_per_eu(2, 2)))
void fused_attn(
    const unsigned short* __restrict__ Q,    // [B][N][C] bf16 (bias included)
    const unsigned short* __restrict__ K,    // [B][M][C] bf16 (bias included)
    const unsigned short* __restrict__ Vt,   // [B][C][M] bf16 (bias included)
    float* __restrict__ Z)                   // [B][N][C] +=
{
    extern __shared__ __align__(16) unsigned char smem[];
    unsigned char* Ks = smem;                // K [64][256] bf16, row stride 512B, swizzled
    unsigned char* Vs = smem + 32768;        // V [256][64] bf16, row stride 128B, swizzled
    unsigned char* Ps = smem + 65536;        // P [128][64] bf16, row stride 128B, swizzled
    __shared__ float rsl[2][128];

    int z = blockIdx.z;
    int n0 = blockIdx.x * 128;
    int t = threadIdx.x, w = t >> 6, l = t & 63, g = l >> 4, c16 = l & 15;
    int wn = w >> 1, wc = w & 1;   // wave grid: 4 n-rows x 2 cols

    const unsigned short* Qb = Q + ((size_t)z * NN + n0) * CC;
    const unsigned short* Kz = K + (size_t)z * MM * CC;
    const unsigned short* Vz = Vt + (size_t)z * CC * MM;

    // Q fragments in registers: rows wn*32 + fi*16 + c16, k = ks*32 + g*8  (64 VGPR)
    s16x8 q[2][8];
#pragma unroll
    for (int fi = 0; fi < 2; ++fi)
#pragma unroll
        for (int ks = 0; ks < 8; ++ks)
            q[fi][ks] = *(const s16x8*)&Qb[(size_t)(wn * 32 + fi * 16 + c16) * CC + ks * 32 + g * 8];

    f32x4 o[2][8];
#pragma unroll
    for (int fi = 0; fi < 2; ++fi)
#pragma unroll
        for (int fj = 0; fj < 8; ++fj) o[fi][fj] = (f32x4){0.f, 0.f, 0.f, 0.f};
    float rs[2][4];
#pragma unroll
    for (int fi = 0; fi < 2; ++fi)
#pragma unroll
        for (int r = 0; r < 4; ++r) rs[fi][r] = 0.f;

    // prefetch K and V tile 0 into registers (16+16 VGPR)
    uint4 kr[4], vr[4];
#pragma unroll
    for (int i = 0; i < 4; ++i) {
        int c = i * 512 + t, krow = c >> 5, kc = c & 31;
        kr[i] = *(const uint4*)&Kz[(size_t)krow * CC + kc * 8];
        int vrow = c >> 3, mc = c & 7;
        vr[i] = *(const uint4*)&Vz[(size_t)vrow * MM + mc * 8];
    }

    for (int mt = 0; mt < 16; ++mt) {
        __syncthreads();                       // sync1: prev QK/PV reads done (vmcnt drain = kr/vr, needed now)
        // store K tile and V tile (swizzled)
#pragma unroll
        for (int i = 0; i < 4; ++i) {
            int c = i * 512 + t, krow = c >> 5, kc = c & 31;
            *(uint4*)(Ks + krow * 512 + ((kc * 16) ^ ((krow & 7) << 4))) = kr[i];
            int vrow = c >> 3, mc = c & 7;
            *(uint4*)(Vs + vrow * 128 + ((mc * 16) ^ ((vrow & 7) << 4))) = vr[i];
        }
        __syncthreads();                       // sync2: K,V visible
        // prefetch next K+V tiles -- overlaps QK+exp+PV, drained at next sync1
        if (mt < 15) {
            int m1 = (mt + 1) * 64;
#pragma unroll
            for (int i = 0; i < 4; ++i) {
                int c = i * 512 + t, krow = c >> 5, kc = c & 31;
                kr[i] = *(const uint4*)&Kz[(size_t)(m1 + krow) * CC + kc * 8];
                int vrow = c >> 3, mc = c & 7;
                vr[i] = *(const uint4*)&Vz[(size_t)vrow * MM + m1 + mc * 8];
            }
        }
        __builtin_amdgcn_sched_barrier(0);     // pin load issue before QK
        // QK^T
        f32x4 sacc[2][2];
#pragma unroll
        for (int fi = 0; fi < 2; ++fi)
#pragma unroll
            for (int fj = 0; fj < 2; ++fj) sacc[fi][fj] = (f32x4){0.f, 0.f, 0.f, 0.f};
        __builtin_amdgcn_s_setprio(1);
#pragma unroll
        for (int ks = 0; ks < 8; ++ks) {
            s16x8 kf[2];
#pragma unroll
            for (int fj = 0; fj < 2; ++fj) {
                int mr = wc * 32 + fj * 16 + c16;
                kf[fj] = *(const s16x8*)(Ks + ((mr * 512 + ks * 64 + g * 16) ^ ((mr & 7) << 4)));
            }
#pragma unroll
            for (int fi = 0; fi < 2; ++fi)
#pragma unroll
                for (int fj = 0; fj < 2; ++fj)
                    sacc[fi][fj] = __builtin_amdgcn_mfma_f32_16x16x32_bf16(q[fi][ks], kf[fj], sacc[fi][fj], 0, 0, 0);
        }
        __builtin_amdgcn_s_setprio(0);
        // exp -> P (LDS, swizzled), rsum partials
#pragma unroll
        for (int fi = 0; fi < 2; ++fi)
#pragma unroll
            for (int fj = 0; fj < 2; ++fj)
#pragma unroll
                for (int r = 0; r < 4; ++r) {
                    float e = __expf(sacc[fi][fj][r] * SCALE);
                    unsigned short h = f2bf(e);
                    int nr = wn * 32 + fi * 16 + g * 4 + r;
                    int mc = wc * 32 + fj * 16 + c16;
                    *(unsigned short*)(Ps + ((nr * 128 + mc * 2) ^ ((nr & 7) << 4))) = h;
                    rs[fi][r] += bf2f(h);
                }
        // sync3: P visible. Raw barrier + lgkmcnt only -- keep prefetch vmcnt outstanding.
        asm volatile("s_waitcnt lgkmcnt(0)" ::: "memory");
        __builtin_amdgcn_s_barrier();
        __builtin_amdgcn_sched_barrier(0);
        // PV: O += P · V
        __builtin_amdgcn_s_setprio(1);
#pragma unroll
        for (int ks2 = 0; ks2 < 2; ++ks2) {
            s16x8 pa[2];
#pragma unroll
            for (int fi = 0; fi < 2; ++fi) {
                int nr = wn * 32 + fi * 16 + c16;
                pa[fi] = *(const s16x8*)(Ps + ((nr * 128 + ks2 * 64 + g * 16) ^ ((nr & 7) << 4)));
            }
#pragma unroll
            for (int fj = 0; fj < 8; ++fj) {
                int er = wc * 128 + fj * 16 + c16;
                s16x8 vb = *(const s16x8*)(Vs + ((er * 128 + ks2 * 64 + g * 16) ^ ((er & 7) << 4)));
#pragma unroll
                for (int fi = 0; fi < 2; ++fi)
                    o[fi][fj] = __builtin_amdgcn_mfma_f32_16x16x32_bf16(pa[fi], vb, o[fi][fj], 0, 0, 0);
            }
        }
        __builtin_amdgcn_s_setprio(0);
    }

    // cross-lane + cross-wave rsum
#pragma unroll
    for (int fi = 0; fi < 2; ++fi)
#pragma unroll
        for (int r = 0; r < 4; ++r) {
            float v = rs[fi][r];
            v += __shfl_xor(v, 1); v += __shfl_xor(v, 2);
            v += __shfl_xor(v, 4); v += __shfl_xor(v, 8);
            if (c16 == 0) rsl[wc][wn * 32 + fi * 16 + g * 4 + r] = v;
        }
    __syncthreads();
    float* Zb = Z + ((size_t)z * NN + n0) * CC;
#pragma unroll
    for (int fi = 0; fi < 2; ++fi)
#pragma unroll
        for (int r = 0; r < 4; ++r) {
            int nr = wn * 32 + fi * 16 + g * 4 + r;
            float inv = 1.0f / (rsl[0][nr] + rsl[1][nr]);
#pragma unroll
            for (int fj = 0; fj < 8; ++fj) {
                int e = wc * 128 + fj * 16 + c16;
                Zb[(size_t)nr * CC + e] += o[fi][fj][r] * inv;
            }
        }
}

// BN stats: per-channel sum and sumsq over B*N rows of Z [B*N][C]
__global__ __launch_bounds__(256) void bn_stats_kernel(const float* __restrict__ Z, float* __restrict__ bn) {
    int blk = blockIdx.x, e = threadIdx.x;
    const float* p = Z + (size_t)blk * 256 * CC + e;
    float s1 = 0.f, s2 = 0.f;
    for (int r = 0; r < 256; ++r) { float v = p[(size_t)r * CC]; s1 += v; s2 += v * v; }
    atomicAdd(&bn[e], s1);
    atomicAdd(&bn[CC + e], s2);
}

// normalize + relu + transpose [B][N][C] -> [B][C][N]
__global__ __launch_bounds__(256) void bn_apply_kernel(const float* __restrict__ Z, const float* __restrict__ bn,
                                                       const float* __restrict__ gamma, const float* __restrict__ beta,
                                                       float* __restrict__ out) {
    int b = blockIdx.z, e0 = blockIdx.y * 32, n0 = blockIdx.x * 32, t = threadIdx.x;
    __shared__ float tile[32][33];
    int c = t & 31, r0 = (t >> 5) * 4;
#pragma unroll
    for (int q = 0; q < 4; ++q)
        tile[r0 + q][c] = Z[((size_t)b * NN + n0 + r0 + q) * CC + e0 + c];
    __syncthreads();
    int n = t & 31, er0 = (t >> 5) * 4;
    const float invcnt = 1.0f / (BB * NN);
#pragma unroll
    for (int q = 0; q < 4; ++q) {
        int e = e0 + er0 + q;
        float mean = bn[e] * invcnt;
        float var = bn[CC + e] * invcnt - mean * mean;
        float rsq = rsqrtf(var + EPSV);
        float v = (tile[n][er0 + q] - mean) * rsq * gamma[e] + beta[e];
        out[((size_t)b * CC + e) * NN + n0 + n] = fmaxf(v, 0.f);
    }
}

extern "C" void kernel_launch(void* const* d_in, const int* in_sizes, int n_in,
                              void* d_out, int out_size, void* d_ws, size_t ws_size,
                              hipStream_t stream) {
    const float* x    = (const float*)d_in[0];
    const float* Wq_s = (const float*)d_in[2];  const float* bq_s = (const float*)d_in[3];
    const float* Wk_s = (const float*)d_in[4];  const float* bk_s = (const float*)d_in[5];
    const float* Wv_s = (const float*)d_in[6];  const float* bv_s = (const float*)d_in[7];
    const float* Wo_s = (const float*)d_in[8];  const float* bo_s = (const float*)d_in[9];
    const float* Wq_g = (const float*)d_in[10]; const float* bq_g = (const float*)d_in[11];
    const float* Wk_g = (const float*)d_in[12]; const float* bk_g = (const float*)d_in[13];
    const float* Wv_g = (const float*)d_in[14]; const float* bv_g = (const float*)d_in[15];
    const float* Wo_g = (const float*)d_in[16]; const float* bo_g = (const float*)d_in[17];
    const float* Wf   = (const float*)d_in[18]; const float* bf   = (const float*)d_in[19];
    const float* gamma = (const float*)d_in[20]; const float* beta = (const float*)d_in[21];

    float* ws    = (float*)d_ws;
    float* mu    = ws + OFF_MU;
    float* score = ws + OFF_SCORE;
    int*   idx_s = (int*)(ws + OFF_IDX);
    int*   idx_g = idx_s + BB * MM;
    float* U     = ws + OFF_U;
    float* Wvz   = ws + OFF_WVZ;
    float* Wf12  = ws + OFF_WF12;
    float* bvz   = ws + OFF_BVZ;
    float* bz    = ws + OFF_BZ;
    unsigned short* Wf12_16 = (unsigned short*)(ws + OFF_W16);
    unsigned short* Wq16    = Wf12_16 + 65536;
    unsigned short* Wk16    = Wq16 + 65536;
    unsigned short* Wvz16   = Wk16 + 65536;
    unsigned short* Xg16 = (unsigned short*)(ws + OFF_XG);
    unsigned short* K16  = (unsigned short*)(ws + OFF_K16);
    unsigned short* Vt16 = (unsigned short*)(ws + OFF_VT16);
    float* Z     = ws + OFF_Z;
    float* bn    = ws + OFF_BN;
    // d_out doubles as scratch: first half Q16, second half xT16 (both dead before bn_apply)
    unsigned short* Q16  = (unsigned short*)d_out;
    unsigned short* xT16 = Q16 + (size_t)BB * NN * CC;

    zero_bn_kernel<<<1, 256, 0, stream>>>(bn);
    mean_kernel<<<dim3(CC, BB), 256, 0, stream>>>(x, mu);
    zero_rsum_kernel<<<BB * NN / 256, 256, 0, stream>>>(score);
    transpose_score_kernel<<<dim3(NN / 32, CC / 32, BB), 256, 0, stream>>>(x, mu, xT16, score);
    select_kernel<<<BB, 1024, 0, stream>>>(score, idx_s, idx_g);
    wf12_kernel<<<CC, 256, 0, stream>>>(Wf, Wf12);
    bz_kernel<<<1, 256, 0, stream>>>(Wf, bf, bo_s, bo_g, bz);
    conv_bf16_kernel<<<64, 256, 0, stream>>>(Wf12, Wf12_16);
    // Z = xT @ Wf12^T + bz  (residual x through both conv halves)
    gemm_bt<0><<<dim3(512, 2, 1), 256, 0, stream>>>(xT16, 0, Wf12_16, 0, bz, Z, 0, CC);

    for (int br = 0; br < 2; ++br) {
        const float* Wo = br ? Wo_g : Wo_s;
        const float* Wv = br ? Wv_g : Wv_s;  const float* bv = br ? bv_g : bv_s;
        const float* Wk = br ? Wk_g : Wk_s;  const float* bk = br ? bk_g : bk_s;
        const float* Wq = br ? Wq_g : Wq_s;  const float* bq = br ? bq_g : bq_s;
        int* idx = br ? idx_g : idx_s;
        int aoff = br ? CC : 0;
        // U = Wf_half @ Wo ; Wvz = U @ Wv ; bvz = U @ bv
        smallmm_kernel<<<CC, 256, 0, stream>>>(Wf, 2 * CC, aoff, Wo, U);
        smallmm_kernel<<<CC, 256, 0, stream>>>(U, CC, 0, Wv, Wvz);
        bvz_kernel<<<1, 256, 0, stream>>>(U, bv, bvz);
        conv_bf16_kernel<<<64, 256, 0, stream>>>(Wq, Wq16);
        conv_bf16_kernel<<<64, 256, 0, stream>>>(Wk, Wk16);
        conv_bf16_kernel<<<64, 256, 0, stream>>>(Wvz, Wvz16);
        // gather context rows once, then all projections are plain A*B^T GEMMs
        gather_kernel<<<BB * MM / 4, 256, 0, stream>>>(xT16, idx, Xg16);
        gemm_bt<1><<<dim3(BB * MM / 128, 2, 1), 256, 0, stream>>>(Xg16, 0, Wk16, 0, bk, K16, 0, CC);
        gemm_bt<2><<<dim3(2, 8, BB), 256, 0, stream>>>(Wvz16, 0, Xg16, (size_t)MM * CC, bvz,
                                                       Vt16, (size_t)CC * MM, MM);
        gemm_bt<1><<<dim3(512, 2, 1), 256, 0, stream>>>(xT16, 0, Wq16, 0, bq, Q16, 0, CC);

        // fused flash attention: Z += softmax(Q·K^T/16)·V  (P never touches HBM)
        fused_attn<<<dim3(NN / 128, 1, BB), 512, 81920, stream>>>(Q16, K16, Vt16, Z);
    }

    bn_stats_kernel<<<BB * NN / 256, 256, 0, stream>>>(Z, bn);
    bn_apply_kernel<<<dim3(NN / 32, CC / 32, BB), 256, 0, stream>>>(Z, bn, gamma, beta, (float*)d_out);
}

// Round 9
// 624.067 us; speedup vs baseline: 1.8017x; 1.4398x over previous
//
#include <hip/hip_runtime.h>

#define BB 16
#define CC 256
#define NN 4096
#define MM 1024
#define EPSV 1e-5f
#define SCALE (1.0f/16.0f)   // 1/sqrt(C)

// ---- workspace layout (float offsets). Fixed part 23,499,776 floats = ~94 MB ----
#define OFF_MU    0            // 4096
#define OFF_SCORE 4096         // 65536   (dead after select)
#define OFF_IDX   69632        // 32768 ints (idx_s then idx_g)
#define OFF_U     102400       // 65536
#define OFF_WVZ   167936       // 65536
#define OFF_WF12  233472       // 65536
#define OFF_BVZ   299008       // 256
#define OFF_BZ    299264       // 256
#define OFF_W16   299520       // 4 bf16 weight mats = 131072 floats
#define OFF_XG    430592       // Xg bf16 [16*1024][256] = 2097152 floats
#define OFF_K16   2527744      // K bf16 [B][M][C] = 2097152 floats
#define OFF_VT16  4624896      // Vt bf16 [B][C][M] = 2097152 floats
#define OFF_Z     6722048      // 16777216 floats
#define OFF_BN    23499264     // 512
#define FIXED_F   23499776     // end of fixed region (floats)

typedef __attribute__((ext_vector_type(8))) short s16x8;
typedef __attribute__((ext_vector_type(4))) float f32x4;

__device__ __forceinline__ unsigned short f2bf(float f) {
    unsigned int u = __float_as_uint(f);
    return (unsigned short)((u + 0x7FFFu + ((u >> 16) & 1u)) >> 16);
}
__device__ __forceinline__ float bf2f(unsigned short h) {
    return __uint_as_float(((unsigned int)h) << 16);
}

__global__ __launch_bounds__(256) void zero_bn_kernel(float* bn) {
    int t = threadIdx.x;
    bn[t] = 0.f; bn[t + CC] = 0.f;
}

__global__ __launch_bounds__(256) void zero_rsum_kernel(float* r) {
    r[blockIdx.x * 256 + threadIdx.x] = 0.f;
}

// mu[b,c] = mean over n of x[b,c,n]  (float4 loads, 4 iters/thread)
__global__ __launch_bounds__(256) void mean_kernel(const float* __restrict__ x, float* __restrict__ mu) {
    int c = blockIdx.x, b = blockIdx.y, t = threadIdx.x;
    const float4* p = (const float4*)(x + ((size_t)b * CC + c) * NN);
    float s = 0.f;
    for (int n = t; n < NN / 4; n += 256) { float4 v = p[n]; s += (v.x + v.y) + (v.z + v.w); }
    __shared__ float red[256];
    red[t] = s; __syncthreads();
    for (int w = 128; w > 0; w >>= 1) { if (t < w) red[t] += red[t + w]; __syncthreads(); }
    if (t == 0) mu[b * CC + c] = red[0] * (1.0f / NN);
}

// x [B][C][N] f32 -> xT16 [B][N][C] bf16, fused with score accumulation
__global__ __launch_bounds__(256) void transpose_score_kernel(const float* __restrict__ x,
                                                              const float* __restrict__ mu,
                                                              unsigned short* __restrict__ xT,
                                                              float* __restrict__ score) {
    __shared__ float tile[32][33];
    __shared__ float smu[32];
    int b = blockIdx.z, c0 = blockIdx.y * 32, n0 = blockIdx.x * 32, t = threadIdx.x;
    int nl = t & 31, cr = t >> 5;
    if (t < 32) smu[t] = mu[b * CC + c0 + t];
#pragma unroll
    for (int q = 0; q < 4; ++q)
        tile[cr + q * 8][nl] = x[((size_t)b * CC + c0 + cr + q * 8) * NN + n0 + nl];
    __syncthreads();
    int nr = t >> 3, cq = t & 7;
    uint2 p;
    p.x = (unsigned int)f2bf(tile[cq * 4 + 0][nr]) | ((unsigned int)f2bf(tile[cq * 4 + 1][nr]) << 16);
    p.y = (unsigned int)f2bf(tile[cq * 4 + 2][nr]) | ((unsigned int)f2bf(tile[cq * 4 + 3][nr]) << 16);
    *(uint2*)&xT[((size_t)b * NN + n0 + nr) * CC + c0 + cq * 4] = p;
    int n = t & 31, cseg = t >> 5;
    float part = 0.f;
#pragma unroll
    for (int q = 0; q < 4; ++q) {
        float d = tile[cseg * 4 + q][n] - smu[cseg * 4 + q];
        part += d * d;
    }
    __syncthreads();
    tile[n][cseg] = part;
    __syncthreads();
    if (t < 32) {
        float s = 0.f;
#pragma unroll
        for (int j = 0; j < 8; ++j) s += tile[t][j];
        atomicAdd(&score[(size_t)b * NN + n0 + t], s);
    }
}

// radix-select: per batch, top-1024 set -> idx_s, bottom-1024 set -> idx_g (order arbitrary)
__global__ __launch_bounds__(1024) void select_kernel(const float* __restrict__ score,
                                                      int* __restrict__ idx_s, int* __restrict__ idx_g) {
    int b = blockIdx.x, t = threadIdx.x;
    __shared__ unsigned int keys[NN];
    __shared__ unsigned int hist[256];
    __shared__ unsigned int sbin, skrem;
    __shared__ int outcnt, eqcnt;
    __shared__ int eqidx[NN];
    for (int q = t; q < NN; q += 1024) keys[q] = __float_as_uint(score[(size_t)b * NN + q]);
    __syncthreads();
    for (int r = 0; r < 2; ++r) {
        unsigned int flip = r ? 0xFFFFFFFFu : 0u;
        unsigned int prefix = 0u, pmask = 0u;
        unsigned int k = MM;
        for (int pass = 0; pass < 4; ++pass) {
            int shift = 24 - 8 * pass;
            if (t < 256) hist[t] = 0u;
            __syncthreads();
            for (int q = t; q < NN; q += 1024) {
                unsigned int kv = keys[q] ^ flip;
                if ((kv & pmask) == prefix) atomicAdd(&hist[(kv >> shift) & 255u], 1u);
            }
            __syncthreads();
            for (int off = 1; off < 256; off <<= 1) {
                unsigned int v = 0u;
                if (t < 256) v = hist[t] + ((t + off < 256) ? hist[t + off] : 0u);
                __syncthreads();
                if (t < 256) hist[t] = v;
                __syncthreads();
            }
            if (t < 256) {
                unsigned int sj = hist[t], sj1 = (t < 255) ? hist[t + 1] : 0u;
                if (sj >= k && sj1 < k) { sbin = (unsigned int)t; skrem = k - sj1; }
            }
            __syncthreads();
            prefix |= sbin << shift;
            pmask |= 0xFFu << shift;
            k = skrem;
            __syncthreads();
        }
        unsigned int T = prefix;
        unsigned int krem = k;
        int* outp = r ? idx_g : idx_s;
        if (t == 0) { outcnt = 0; eqcnt = 0; }
        __syncthreads();
        for (int q = t; q < NN; q += 1024) {
            unsigned int kv = keys[q] ^ flip;
            if (kv > T) { int pp = atomicAdd(&outcnt, 1); outp[(size_t)b * MM + pp] = q; }
            else if (kv == T) { int pp = atomicAdd(&eqcnt, 1); eqidx[pp] = q; }
        }
        __syncthreads();
        int ne = eqcnt;
        for (int i = t; i < ne; i += 1024) {
            int me = eqidx[i];
            int rank = 0;
            for (int j = 0; j < ne; ++j) rank += (eqidx[j] < me) ? 1 : 0;
            if (rank < (int)krem) { int pp = atomicAdd(&outcnt, 1); outp[(size_t)b * MM + pp] = me; }
        }
        __syncthreads();
    }
}

__global__ __launch_bounds__(256) void smallmm_kernel(const float* __restrict__ A, int lda, int aoff,
                                                      const float* __restrict__ Bm, float* __restrict__ Cm) {
    int e = blockIdx.x, t = threadIdx.x;
    __shared__ float arow[CC];
    arow[t] = A[e * lda + aoff + t];
    __syncthreads();
    float acc = 0.f;
    for (int k = 0; k < CC; ++k) acc += arow[k] * Bm[k * CC + t];
    Cm[e * CC + t] = acc;
}

__global__ __launch_bounds__(256) void bvz_kernel(const float* __restrict__ U, const float* __restrict__ bv,
                                                  float* __restrict__ bvz) {
    int e = threadIdx.x;
    float acc = 0.f;
    for (int d = 0; d < CC; ++d) acc += U[e * CC + d] * bv[d];
    bvz[e] = acc;
}

__global__ __launch_bounds__(256) void bz_kernel(const float* __restrict__ Wf, const float* __restrict__ bf,
                                                 const float* __restrict__ bo_s, const float* __restrict__ bo_g,
                                                 float* __restrict__ bz) {
    int e = threadIdx.x;
    float acc = bf[e];
    for (int c = 0; c < CC; ++c)
        acc += Wf[e * 2 * CC + c] * bo_s[c] + Wf[e * 2 * CC + CC + c] * bo_g[c];
    bz[e] = acc;
}

__global__ __launch_bounds__(256) void wf12_kernel(const float* __restrict__ Wf, float* __restrict__ Wf12) {
    int e = blockIdx.x, c = threadIdx.x;
    Wf12[e * CC + c] = Wf[e * 2 * CC + c] + Wf[e * 2 * CC + CC + c];
}

__global__ __launch_bounds__(256) void conv_bf16_kernel(const float* __restrict__ src,
                                                        unsigned short* __restrict__ dst) {
    int i = blockIdx.x * 256 + threadIdx.x;
    float4 v = *(const float4*)(src + (size_t)i * 4);
    uint2 p;
    p.x = (unsigned int)f2bf(v.x) | ((unsigned int)f2bf(v.y) << 16);
    p.y = (unsigned int)f2bf(v.z) | ((unsigned int)f2bf(v.w) << 16);
    *(uint2*)&dst[(size_t)i * 4] = p;
}

__global__ __launch_bounds__(256) void gather_kernel(const unsigned short* __restrict__ xT,
                                                     const int* __restrict__ idx,
                                                     unsigned short* __restrict__ Xg) {
    int row = blockIdx.x * 4 + (threadIdx.x >> 6);
    int l = threadIdx.x & 63;
    int b = row >> 10, m = row & (MM - 1);
    int src = idx[b * MM + m];
    *(uint2*)&Xg[(size_t)row * CC + l * 4] =
        *(const uint2*)&xT[((size_t)b * NN + src) * CC + l * 4];
}

// ---- generic bf16 MFMA GEMM: out[i][j] = sum_k A[i][k]*Bw[j][k] (+bias), 128x128 tile ----
template<int OMODE>
__global__ __launch_bounds__(256, 3) void gemm_bt(
    const unsigned short* __restrict__ A, size_t a_bs,
    const unsigned short* __restrict__ Bw, size_t b_bs,
    const float* __restrict__ bias,
    void* __restrict__ outp, size_t o_bs, int ldo)
{
    __shared__ __align__(16) unsigned short As[128 * 32];
    __shared__ __align__(16) unsigned short Bs[128 * 32];
    int z = blockIdx.z;
    const unsigned short* Ab = A + z * a_bs + (size_t)blockIdx.x * 128 * CC;
    const unsigned short* Bb = Bw + z * b_bs + (size_t)blockIdx.y * 128 * CC;
    int t = threadIdx.x, w = t >> 6, l = t & 63, g = l >> 4, c16 = l & 15;
    int wi = w >> 1, wj = w & 1;
    int srow = t >> 2, skq = (t & 3) * 8;

    f32x4 acc[4][4];
#pragma unroll
    for (int a = 0; a < 4; ++a)
#pragma unroll
        for (int bq = 0; bq < 4; ++bq) acc[a][bq] = (f32x4){0.f, 0.f, 0.f, 0.f};

    for (int ks = 0; ks < 8; ++ks) {
        int k0 = ks * 32;
        uint4 a0 = *(const uint4*)(Ab + (size_t)srow * CC + k0 + skq);
        uint4 a1 = *(const uint4*)(Ab + (size_t)(srow + 64) * CC + k0 + skq);
        uint4 b0 = *(const uint4*)(Bb + (size_t)srow * CC + k0 + skq);
        uint4 b1 = *(const uint4*)(Bb + (size_t)(srow + 64) * CC + k0 + skq);
        __syncthreads();
        *(uint4*)&As[srow * 32 + skq] = a0;
        *(uint4*)&As[(srow + 64) * 32 + skq] = a1;
        *(uint4*)&Bs[srow * 32 + skq] = b0;
        *(uint4*)&Bs[(srow + 64) * 32 + skq] = b1;
        __syncthreads();
        s16x8 af[4], bf4[4];
#pragma unroll
        for (int fi = 0; fi < 4; ++fi)
            af[fi] = *(const s16x8*)&As[(wi * 64 + fi * 16 + c16) * 32 + g * 8];
#pragma unroll
        for (int fj = 0; fj < 4; ++fj)
            bf4[fj] = *(const s16x8*)&Bs[(wj * 64 + fj * 16 + c16) * 32 + g * 8];
#pragma unroll
        for (int fi = 0; fi < 4; ++fi)
#pragma unroll
            for (int fj = 0; fj < 4; ++fj)
                acc[fi][fj] = __builtin_amdgcn_mfma_f32_16x16x32_bf16(af[fi], bf4[fj], acc[fi][fj], 0, 0, 0);
    }

    int i0 = blockIdx.x * 128 + wi * 64, j0 = blockIdx.y * 128 + wj * 64;
#pragma unroll
    for (int fi = 0; fi < 4; ++fi) {
#pragma unroll
        for (int fj = 0; fj < 4; ++fj) {
            int colg = j0 + fj * 16 + c16;
#pragma unroll
            for (int r = 0; r < 4; ++r) {
                int rowg = i0 + fi * 16 + g * 4 + r;
                float v = acc[fi][fj][r] + (OMODE == 2 ? bias[rowg] : bias[colg]);
                if (OMODE == 0)
                    ((float*)outp)[z * o_bs + (size_t)rowg * ldo + colg] = v;
                else
                    ((unsigned short*)outp)[z * o_bs + (size_t)rowg * ldo + colg] = f2bf(v);
            }
        }
    }
}

// ---- fused flash-style attention: Z[z][n][e] += (exp(Q·K^T/16)·V) / rsum[n] ----
// Round-6 compute body (128 rows, 512 thr, R=2, waves_per_eu(2,2)) with staging moved
// to global_load_lds + double-buffered K/V LDS (2x32KB each + P 16KB = 145KB, 1 blk/CU):
//  - staging uses ZERO VGPRs (rounds 7/8 proved any extra prefetch-register lifetime
//    past the ~128-VGPR class budget spills to scratch: WRITE 478-668MB);
//  - tile-top vmcnt(0) waits on loads issued a FULL TILE earlier -> latency hidden
//    (round 6's drain hit loads issued ~200cyc before the barrier = the ~55% stall);
//  - 2 barriers/tile (was 4). Swizzle via linear LDS dest + inverse-XOR global src
//    + XOR'd reads (XOR is an involution; row index untouched by it).
__global__ __attribute__((amdgpu_flat_work_group_size(512, 512)))
__attribute__((amdgpu_waves_per_eu(2, 2)))
void fused_attn(
    const unsigned short* __restrict__ Q,    // [B][N][C] bf16 (bias included)
    const unsigned short* __restrict__ K,    // [B][M][C] bf16 (bias included)
    const unsigned short* __restrict__ Vt,   // [B][C][M] bf16 (bias included)
    float* __restrict__ Z)                   // [B][N][C] +=
{
    extern __shared__ __align__(16) unsigned char smem[];
    // layout: [K0 32K][K1 32K][V0 32K][V1 32K][P 16K][rsl 1K] = 148480 B
    unsigned char* Ps = smem + 131072;
    float* rsl = (float*)(smem + 147456);

    int z = blockIdx.z;
    int n0 = blockIdx.x * 128;
    int t = threadIdx.x, w = t >> 6, l = t & 63, g = l >> 4, c16 = l & 15;
    int wn = w >> 1, wc = w & 1;   // wave grid: 4 n-rows x 2 cols

    const unsigned short* Qb = Q + ((size_t)z * NN + n0) * CC;
    const char* Kzb = (const char*)(K + (size_t)z * MM * CC);
    const char* Vzb = (const char*)(Vt + (size_t)z * CC * MM);

    // Q fragments in registers: rows wn*32 + fi*16 + c16, k = ks*32 + g*8  (64 VGPR)
    s16x8 q[2][8];
#pragma unroll
    for (int fi = 0; fi < 2; ++fi)
#pragma unroll
        for (int ks = 0; ks < 8; ++ks)
            q[fi][ks] = *(const s16x8*)&Qb[(size_t)(wn * 32 + fi * 16 + c16) * CC + ks * 32 + g * 8];

    f32x4 o[2][8];
#pragma unroll
    for (int fi = 0; fi < 2; ++fi)
#pragma unroll
        for (int fj = 0; fj < 8; ++fj) o[fi][fj] = (f32x4){0.f, 0.f, 0.f, 0.f};
    float rs[2][4];
#pragma unroll
    for (int fi = 0; fi < 2; ++fi)
#pragma unroll
        for (int r = 0; r < 4; ++r) rs[fi][r] = 0.f;

    // global_load_lds staging: LDS linear, global source pre-XOR'd per lane.
    // K tile: 32KB, rows 64 x 512B; chunk = 1KB (64 lanes x 16B); 8 waves x 4 chunks.
    auto issueK = [&](int buf, int m0) {
#pragma unroll
        for (int j = 0; j < 4; ++j) {
            int cid = w * 4 + j;
            int row = cid * 2 + (l >> 5);
            int srcoff = ((l & 31) * 16) ^ ((row & 7) << 4);
            const char* gp = Kzb + (size_t)(m0 + row) * 512 + srcoff;
            __builtin_amdgcn_global_load_lds(
                (const __attribute__((address_space(1))) void*)gp,
                (__attribute__((address_space(3))) void*)(smem + buf * 32768 + cid * 1024),
                16, 0, 0);
        }
    };
    // V tile: 32KB, rows 256 x 128B
    auto issueV = [&](int buf, int m0) {
#pragma unroll
        for (int j = 0; j < 4; ++j) {
            int cid = w * 4 + j;
            int row = cid * 8 + (l >> 3);
            int srcoff = ((l & 7) * 16) ^ ((row & 7) << 4);
            const char* gp = Vzb + (size_t)row * 2048 + (size_t)m0 * 2 + srcoff;
            __builtin_amdgcn_global_load_lds(
                (const __attribute__((address_space(1))) void*)gp,
                (__attribute__((address_space(3))) void*)(smem + 65536 + buf * 32768 + cid * 1024),
                16, 0, 0);
        }
    };

    issueK(0, 0);
    issueV(0, 0);

    for (int mt = 0; mt < 16; ++mt) {
        int cur = mt & 1;
        asm volatile("s_waitcnt vmcnt(0)" ::: "memory");   // buf[cur] gll done (issued ~1 tile ago)
        __builtin_amdgcn_s_barrier();                      // all waves: buf[cur] ready, buf[1-cur] free
        __builtin_amdgcn_sched_barrier(0);
        if (mt < 15) {
            issueK(1 - cur, (mt + 1) * 64);
            issueV(1 - cur, (mt + 1) * 64);
        }
        __builtin_amdgcn_sched_barrier(0);
        const unsigned char* Ks = smem + cur * 32768;
        const unsigned char* Vs = smem + 65536 + cur * 32768;

        // QK^T
        f32x4 sacc[2][2];
#pragma unroll
        for (int fi = 0; fi < 2; ++fi)
#pragma unroll
            for (int fj = 0; fj < 2; ++fj) sacc[fi][fj] = (f32x4){0.f, 0.f, 0.f, 0.f};
        __builtin_amdgcn_s_setprio(1);
#pragma unroll
        for (int ks = 0; ks < 8; ++ks) {
            s16x8 kf[2];
#pragma unroll
            for (int fj = 0; fj < 2; ++fj) {
                int mr = wc * 32 + fj * 16 + c16;
                kf[fj] = *(const s16x8*)(Ks + ((mr * 512 + ks * 64 + g * 16) ^ ((mr & 7) << 4)));
            }
#pragma unroll
            for (int fi = 0; fi < 2; ++fi)
#pragma unroll
                for (int fj = 0; fj < 2; ++fj)
                    sacc[fi][fj] = __builtin_amdgcn_mfma_f32_16x16x32_bf16(q[fi][ks], kf[fj], sacc[fi][fj], 0, 0, 0);
        }
        __builtin_amdgcn_s_setprio(0);
        // exp -> P (LDS, swizzled), rsum partials
#pragma unroll
        for (int fi = 0; fi < 2; ++fi)
#pragma unroll
            for (int fj = 0; fj < 2; ++fj)
#pragma unroll
                for (int r = 0; r < 4; ++r) {
                    float e = __expf(sacc[fi][fj][r] * SCALE);
                    unsigned short h = f2bf(e);
                    int nr = wn * 32 + fi * 16 + g * 4 + r;
                    int mc = wc * 32 + fj * 16 + c16;
                    *(unsigned short*)(Ps + ((nr * 128 + mc * 2) ^ ((nr & 7) << 4))) = h;
                    rs[fi][r] += bf2f(h);
                }
        // P visible: lgkm-only barrier (keep next-tile gll vmcnt outstanding)
        asm volatile("s_waitcnt lgkmcnt(0)" ::: "memory");
        __builtin_amdgcn_s_barrier();
        __builtin_amdgcn_sched_barrier(0);
        // PV: O += P · V
        __builtin_amdgcn_s_setprio(1);
#pragma unroll
        for (int ks2 = 0; ks2 < 2; ++ks2) {
            s16x8 pa[2];
#pragma unroll
            for (int fi = 0; fi < 2; ++fi) {
                int nr = wn * 32 + fi * 16 + c16;
                pa[fi] = *(const s16x8*)(Ps + ((nr * 128 + ks2 * 64 + g * 16) ^ ((nr & 7) << 4)));
            }
#pragma unroll
            for (int fj = 0; fj < 8; ++fj) {
                int er = wc * 128 + fj * 16 + c16;
                s16x8 vb = *(const s16x8*)(Vs + ((er * 128 + ks2 * 64 + g * 16) ^ ((er & 7) << 4)));
#pragma unroll
                for (int fi = 0; fi < 2; ++fi)
                    o[fi][fj] = __builtin_amdgcn_mfma_f32_16x16x32_bf16(pa[fi], vb, o[fi][fj], 0, 0, 0);
            }
        }
        __builtin_amdgcn_s_setprio(0);
    }

    // cross-lane + cross-wave rsum
#pragma unroll
    for (int fi = 0; fi < 2; ++fi)
#pragma unroll
        for (int r = 0; r < 4; ++r) {
            float v = rs[fi][r];
            v += __shfl_xor(v, 1); v += __shfl_xor(v, 2);
            v += __shfl_xor(v, 4); v += __shfl_xor(v, 8);
            if (c16 == 0) rsl[wc * 128 + wn * 32 + fi * 16 + g * 4 + r] = v;
        }
    __syncthreads();
    float* Zb = Z + ((size_t)z * NN + n0) * CC;
#pragma unroll
    for (int fi = 0; fi < 2; ++fi)
#pragma unroll
        for (int r = 0; r < 4; ++r) {
            int nr = wn * 32 + fi * 16 + g * 4 + r;
            float inv = 1.0f / (rsl[nr] + rsl[128 + nr]);
#pragma unroll
            for (int fj = 0; fj < 8; ++fj) {
                int e = wc * 128 + fj * 16 + c16;
                Zb[(size_t)nr * CC + e] += o[fi][fj][r] * inv;
            }
        }
}

// BN stats: per-channel sum and sumsq over B*N rows of Z [B*N][C]
__global__ __launch_bounds__(256) void bn_stats_kernel(const float* __restrict__ Z, float* __restrict__ bn) {
    int blk = blockIdx.x, e = threadIdx.x;
    const float* p = Z + (size_t)blk * 256 * CC + e;
    float s1 = 0.f, s2 = 0.f;
    for (int r = 0; r < 256; ++r) { float v = p[(size_t)r * CC]; s1 += v; s2 += v * v; }
    atomicAdd(&bn[e], s1);
    atomicAdd(&bn[CC + e], s2);
}

// normalize + relu + transpose [B][N][C] -> [B][C][N]
__global__ __launch_bounds__(256) void bn_apply_kernel(const float* __restrict__ Z, const float* __restrict__ bn,
                                                       const float* __restrict__ gamma, const float* __restrict__ beta,
                                                       float* __restrict__ out) {
    int b = blockIdx.z, e0 = blockIdx.y * 32, n0 = blockIdx.x * 32, t = threadIdx.x;
    __shared__ float tile[32][33];
    int c = t & 31, r0 = (t >> 5) * 4;
#pragma unroll
    for (int q = 0; q < 4; ++q)
        tile[r0 + q][c] = Z[((size_t)b * NN + n0 + r0 + q) * CC + e0 + c];
    __syncthreads();
    int n = t & 31, er0 = (t >> 5) * 4;
    const float invcnt = 1.0f / (BB * NN);
#pragma unroll
    for (int q = 0; q < 4; ++q) {
        int e = e0 + er0 + q;
        float mean = bn[e] * invcnt;
        float var = bn[CC + e] * invcnt - mean * mean;
        float rsq = rsqrtf(var + EPSV);
        float v = (tile[n][er0 + q] - mean) * rsq * gamma[e] + beta[e];
        out[((size_t)b * CC + e) * NN + n0 + n] = fmaxf(v, 0.f);
    }
}

extern "C" void kernel_launch(void* const* d_in, const int* in_sizes, int n_in,
                              void* d_out, int out_size, void* d_ws, size_t ws_size,
                              hipStream_t stream) {
    const float* x    = (const float*)d_in[0];
    const float* Wq_s = (const float*)d_in[2];  const float* bq_s = (const float*)d_in[3];
    const float* Wk_s = (const float*)d_in[4];  const float* bk_s = (const float*)d_in[5];
    const float* Wv_s = (const float*)d_in[6];  const float* bv_s = (const float*)d_in[7];
    const float* Wo_s = (const float*)d_in[8];  const float* bo_s = (const float*)d_in[9];
    const float* Wq_g = (const float*)d_in[10]; const float* bq_g = (const float*)d_in[11];
    const float* Wk_g = (const float*)d_in[12]; const float* bk_g = (const float*)d_in[13];
    const float* Wv_g = (const float*)d_in[14]; const float* bv_g = (const float*)d_in[15];
    const float* Wo_g = (const float*)d_in[16]; const float* bo_g = (const float*)d_in[17];
    const float* Wf   = (const float*)d_in[18]; const float* bf   = (const float*)d_in[19];
    const float* gamma = (const float*)d_in[20]; const float* beta = (const float*)d_in[21];

    float* ws    = (float*)d_ws;
    float* mu    = ws + OFF_MU;
    float* score = ws + OFF_SCORE;
    int*   idx_s = (int*)(ws + OFF_IDX);
    int*   idx_g = idx_s + BB * MM;
    float* U     = ws + OFF_U;
    float* Wvz   = ws + OFF_WVZ;
    float* Wf12  = ws + OFF_WF12;
    float* bvz   = ws + OFF_BVZ;
    float* bz    = ws + OFF_BZ;
    unsigned short* Wf12_16 = (unsigned short*)(ws + OFF_W16);
    unsigned short* Wq16    = Wf12_16 + 65536;
    unsigned short* Wk16    = Wq16 + 65536;
    unsigned short* Wvz16   = Wk16 + 65536;
    unsigned short* Xg16 = (unsigned short*)(ws + OFF_XG);
    unsigned short* K16  = (unsigned short*)(ws + OFF_K16);
    unsigned short* Vt16 = (unsigned short*)(ws + OFF_VT16);
    float* Z     = ws + OFF_Z;
    float* bn    = ws + OFF_BN;
    // d_out doubles as scratch: first half Q16, second half xT16 (both dead before bn_apply)
    unsigned short* Q16  = (unsigned short*)d_out;
    unsigned short* xT16 = Q16 + (size_t)BB * NN * CC;

    zero_bn_kernel<<<1, 256, 0, stream>>>(bn);
    mean_kernel<<<dim3(CC, BB), 256, 0, stream>>>(x, mu);
    zero_rsum_kernel<<<BB * NN / 256, 256, 0, stream>>>(score);
    transpose_score_kernel<<<dim3(NN / 32, CC / 32, BB), 256, 0, stream>>>(x, mu, xT16, score);
    select_kernel<<<BB, 1024, 0, stream>>>(score, idx_s, idx_g);
    wf12_kernel<<<CC, 256, 0, stream>>>(Wf, Wf12);
    bz_kernel<<<1, 256, 0, stream>>>(Wf, bf, bo_s, bo_g, bz);
    conv_bf16_kernel<<<64, 256, 0, stream>>>(Wf12, Wf12_16);
    // Z = xT @ Wf12^T + bz  (residual x through both conv halves)
    gemm_bt<0><<<dim3(512, 2, 1), 256, 0, stream>>>(xT16, 0, Wf12_16, 0, bz, Z, 0, CC);

    for (int br = 0; br < 2; ++br) {
        const float* Wo = br ? Wo_g : Wo_s;
        const float* Wv = br ? Wv_g : Wv_s;  const float* bv = br ? bv_g : bv_s;
        const float* Wk = br ? Wk_g : Wk_s;  const float* bk = br ? bk_g : bk_s;
        const float* Wq = br ? Wq_g : Wq_s;  const float* bq = br ? bq_g : bq_s;
        int* idx = br ? idx_g : idx_s;
        int aoff = br ? CC : 0;
        // U = Wf_half @ Wo ; Wvz = U @ Wv ; bvz = U @ bv
        smallmm_kernel<<<CC, 256, 0, stream>>>(Wf, 2 * CC, aoff, Wo, U);
        smallmm_kernel<<<CC, 256, 0, stream>>>(U, CC, 0, Wv, Wvz);
        bvz_kernel<<<1, 256, 0, stream>>>(U, bv, bvz);
        conv_bf16_kernel<<<64, 256, 0, stream>>>(Wq, Wq16);
        conv_bf16_kernel<<<64, 256, 0, stream>>>(Wk, Wk16);
        conv_bf16_kernel<<<64, 256, 0, stream>>>(Wvz, Wvz16);
        // gather context rows once, then all projections are plain A*B^T GEMMs
        gather_kernel<<<BB * MM / 4, 256, 0, stream>>>(xT16, idx, Xg16);
        gemm_bt<1><<<dim3(BB * MM / 128, 2, 1), 256, 0, stream>>>(Xg16, 0, Wk16, 0, bk, K16, 0, CC);
        gemm_bt<2><<<dim3(2, 8, BB), 256, 0, stream>>>(Wvz16, 0, Xg16, (size_t)MM * CC, bvz,
                                                       Vt16, (size_t)CC * MM, MM);
        gemm_bt<1><<<dim3(512, 2, 1), 256, 0, stream>>>(xT16, 0, Wq16, 0, bq, Q16, 0, CC);

        // fused flash attention: Z += softmax(Q·K^T/16)·V  (P never touches HBM)
        fused_attn<<<dim3(NN / 128, 1, BB), 512, 148480, stream>>>(Q16, K16, Vt16, Z);
    }

    bn_stats_kernel<<<BB * NN / 256, 256, 0, stream>>>(Z, bn);
    bn_apply_kernel<<<dim3(NN / 32, CC / 32, BB), 256, 0, stream>>>(Z, bn, gamma, beta, (float*)d_out);
}